// Round 1
// baseline (21.206 us; speedup 1.0000x reference)
//
#include <hip/hip_runtime.h>

// BayesianDiffSizeCatEmbeddings: out[b, off_i : off_i+dim_i] =
//   mu_i[idx,:] + softplus(rho_i[idx,:]) * eps_i[idx,:],  idx = X[b,i]
// 8 tables, dims {64,64,32,32,16,16,16,8}, BATCH=16384, out = [16384, 248] f32.
// Pure gather + elementwise; memory-bound (~66 MB total traffic).

constexpr int BATCH = 16384;
constexpr int NCOLS = 8;
constexpr int OUT_ROW = 248;

struct Params {
    const float* mu[NCOLS];
    const float* rho[NCOLS];
    const float* eps[NCOLS];
    const int*   X;     // [BATCH, 8] int32
    float*       out;   // [BATCH, 248] f32
};

// log2(dim/4) per column: dims 64,64,32,32,16,16,16,8 -> quads 16,16,8,8,4,4,4,2
__device__ const int DSHIFT[NCOLS] = {4, 4, 3, 3, 2, 2, 2, 1};
__device__ const int COLOFF[NCOLS] = {0, 64, 128, 160, 192, 208, 224, 240};

__device__ __forceinline__ float softplus_f(float x) {
    // matches jax.nn.softplus = log1p(exp(x)); rho ~ N(-6, 0.1) so no overflow risk,
    // but guard anyway for exactness at large x.
    return (x > 15.0f) ? x : log1pf(__expf(x));
}

__global__ __launch_bounds__(256) void bayes_embed_kernel(Params p) {
    const int col    = blockIdx.y;          // wave-uniform: which table
    const int dshift = DSHIFT[col];         // log2(float4s per row)
    const int coff   = COLOFF[col];         // output column offset
    const int nquads = BATCH << dshift;     // total float4s for this column

    const int t = blockIdx.x * 256 + threadIdx.x;
    if (t >= nquads) return;

    const int b  = t >> dshift;             // batch row
    const int d4 = t & ((1 << dshift) - 1); // float4 index within the row
    const int dim = 4 << dshift;

    const int idx = p.X[b * NCOLS + col];

    const long base = (long)idx * dim + (long)d4 * 4;
    const float4 m = *(const float4*)(p.mu[col]  + base);
    const float4 r = *(const float4*)(p.rho[col] + base);
    const float4 e = *(const float4*)(p.eps[col] + base);

    float4 o;
    o.x = m.x + softplus_f(r.x) * e.x;
    o.y = m.y + softplus_f(r.y) * e.y;
    o.z = m.z + softplus_f(r.z) * e.z;
    o.w = m.w + softplus_f(r.w) * e.w;

    *(float4*)(p.out + (long)b * OUT_ROW + coff + d4 * 4) = o;
}

extern "C" void kernel_launch(void* const* d_in, const int* in_sizes, int n_in,
                              void* d_out, int out_size, void* d_ws, size_t ws_size,
                              hipStream_t stream) {
    Params p;
    for (int i = 0; i < NCOLS; ++i) {
        p.mu[i]  = (const float*)d_in[3 * i + 0];
        p.rho[i] = (const float*)d_in[3 * i + 1];
        p.eps[i] = (const float*)d_in[3 * i + 2];
    }
    p.X   = (const int*)d_in[24];
    p.out = (float*)d_out;

    // Largest column needs BATCH*16 quads = 262144 threads -> 1024 blocks of 256.
    // Smaller columns exit early via the nquads guard (cheap).
    dim3 grid(1024, NCOLS, 1);
    bayes_embed_kernel<<<grid, 256, 0, stream>>>(p);
}